// Round 2
// 394.986 us; speedup vs baseline: 1.0680x; 1.0680x over previous
//
#include <hip/hip_runtime.h>

// ---------------------------------------------------------------------------
// MultiHeadAttention (B=1, N=2925, D_MODEL=1536, 12 heads x 128) on gfx950.
// convert/transpose -> fused QKV bf16-MFMA GEMM (global_load_lds staging) ->
// RMSNorm+3D RoPE (exp2-domain q-scale) -> V transpose -> split-KV flash
// attention (async-staged swizzled tiles, defer-max) -> combine -> O GEMM.
// ---------------------------------------------------------------------------

#define N_TOK 2925
#define DMODEL 1536
#define NHEAD 12
#define HDIM 128
#define KSPLIT 1472           // split-KV boundary (23 tiles of 64)
#define VT_STRIDE 2944        // N_TOK padded to x64; pad MUST be zeroed (NaN hazard)

typedef __attribute__((ext_vector_type(8))) __bf16 bf16x8;
typedef __attribute__((ext_vector_type(4))) float floatx4;

#define MFMA(a, b, c) __builtin_amdgcn_mfma_f32_16x16x32_bf16((a), (b), (c), 0, 0, 0)

static __device__ __forceinline__ unsigned short f2bf(float f) {
    unsigned u = __builtin_bit_cast(unsigned, f);
    return (unsigned short)((u + 0x7fffu + ((u >> 16) & 1u)) >> 16);
}

// async global->LDS 16B/lane (emits global_load_lds_dwordx4).
// LDS dest MUST be wave-uniform-base + lane*16.
static __device__ __forceinline__ void gload_lds16(const unsigned short* g, unsigned short* l) {
    __builtin_amdgcn_global_load_lds((const __attribute__((address_space(1))) void*)g,
                                     (__attribute__((address_space(3))) void*)l, 16, 0, 0);
}

// ---------------------------------------------------------------- convert x
__global__ __launch_bounds__(256) void k_convert_x(const float* __restrict__ x,
                                                   unsigned short* __restrict__ xb, int n) {
    int i = (blockIdx.x * 256 + threadIdx.x) * 4;
    if (i < n) {
        float4 v = *(const float4*)(x + i);
        uint2 o;
        o.x = (unsigned)f2bf(v.x) | ((unsigned)f2bf(v.y) << 16);
        o.y = (unsigned)f2bf(v.z) | ((unsigned)f2bf(v.w) << 16);
        *(uint2*)(xb + i) = o;
    }
}

// ---------------------------------------------- transpose W [k][n] -> Wt [n][k] bf16
__global__ __launch_bounds__(256) void k_transpose_w(const float* __restrict__ W0,
                                                     const float* __restrict__ W1,
                                                     const float* __restrict__ W2,
                                                     const float* __restrict__ W3,
                                                     unsigned short* __restrict__ Wt) {
    __shared__ float tile[32][33];
    const float* W = blockIdx.z == 0 ? W0 : blockIdx.z == 1 ? W1 : blockIdx.z == 2 ? W2 : W3;
    unsigned short* out = Wt + (size_t)blockIdx.z * DMODEL * DMODEL;
    int tx = threadIdx.x, ty = threadIdx.y;           // 32 x 8
    int bx = blockIdx.x * 32, by = blockIdx.y * 32;
#pragma unroll
    for (int i = 0; i < 4; i++)
        tile[ty + 8 * i][tx] = W[(size_t)(by + ty + 8 * i) * DMODEL + bx + tx];
    __syncthreads();
#pragma unroll
    for (int i = 0; i < 4; i++)
        out[(size_t)(bx + ty + 8 * i) * DMODEL + by + tx] = f2bf(tile[tx][ty + 8 * i]);
}

// ------------------------------------------------------------ bf16 MFMA GEMM
// m97 structure: unpadded stride-32 LDS tiles staged via global_load_lds(16B).
__global__ __launch_bounds__(256, 2) void k_gemm(const unsigned short* __restrict__ A,
                                                 const unsigned short* __restrict__ BtBase,
                                                 const float* __restrict__ b0,
                                                 const float* __restrict__ b1,
                                                 const float* __restrict__ b2,
                                                 float* __restrict__ Cbase, int M) {
    const int z = blockIdx.z;
    const unsigned short* Bt = BtBase + (size_t)z * DMODEL * DMODEL;
    const float* bias = (z == 0) ? b0 : (z == 1) ? b1 : b2;
    float* C = Cbase + (size_t)z * M * DMODEL;

    __shared__ __align__(16) unsigned short As[128 * 32];   // [row][k], contiguous
    __shared__ __align__(16) unsigned short Bs[128 * 32];   // [n][k],   contiguous

    const int tid = threadIdx.x;
    const int wave = tid >> 6, lane = tid & 63, quad = lane >> 4, l16 = lane & 15;
    const int wr = wave >> 1, wc = wave & 1;
    const int m0 = blockIdx.y * 128, n0 = blockIdx.x * 128;

    // staging coords: thread covers row r4 (+64 on 2nd issue), 16B col chunk c4
    const int r4 = tid >> 2, c4 = (tid & 3) * 8;
    // NOTE: A rows m0+r4(+64) may exceed M (max 2943 > 2924): reads land in the
    // next ws region (no fault); garbage only reaches acc rows discarded by rg<M.

    floatx4 acc[4][4] = {};

    for (int k0 = 0; k0 < DMODEL; k0 += 32) {
        gload_lds16(A + (size_t)(m0 + r4) * DMODEL + k0 + c4,       &As[r4 * 32 + c4]);
        gload_lds16(A + (size_t)(m0 + r4 + 64) * DMODEL + k0 + c4,  &As[(r4 + 64) * 32 + c4]);
        gload_lds16(Bt + (size_t)(n0 + r4) * DMODEL + k0 + c4,      &Bs[r4 * 32 + c4]);
        gload_lds16(Bt + (size_t)(n0 + r4 + 64) * DMODEL + k0 + c4, &Bs[(r4 + 64) * 32 + c4]);
        __syncthreads();

        bf16x8 af[4], bfm[4];
#pragma unroll
        for (int i = 0; i < 4; i++)
            af[i] = *(const bf16x8*)&As[(wr * 64 + i * 16 + l16) * 32 + quad * 8];
#pragma unroll
        for (int j = 0; j < 4; j++)
            bfm[j] = *(const bf16x8*)&Bs[(wc * 64 + j * 16 + l16) * 32 + quad * 8];
#pragma unroll
        for (int i = 0; i < 4; i++)
#pragma unroll
            for (int j = 0; j < 4; j++)
                acc[i][j] = MFMA(af[i], bfm[j], acc[i][j]);
        __syncthreads();
    }

#pragma unroll
    for (int j = 0; j < 4; j++) {
        int cg = n0 + wc * 64 + j * 16 + l16;
        float bv = bias[cg];
#pragma unroll
        for (int i = 0; i < 4; i++) {
            int rbase = m0 + wr * 64 + i * 16 + quad * 4;
#pragma unroll
            for (int r = 0; r < 4; r++) {
                int rg = rbase + r;
                if (rg < M) C[(size_t)rg * DMODEL + cg] = acc[i][j][r] + bv;
            }
        }
    }
}

// ---------------------------------- fused RMSNorm (full 1536) + 3D RoPE + pack
// q pre-scaled by (1/sqrt(HDIM))*log2(e) -> softmax runs in exp2 domain.
__global__ __launch_bounds__(256) void k_norm_rope(const float* __restrict__ Qf,
                                                   const float* __restrict__ Kf,
                                                   const float* __restrict__ Vf,
                                                   const float* __restrict__ qsc,
                                                   const float* __restrict__ ksc,
                                                   const float* __restrict__ ft,
                                                   const float* __restrict__ fh,
                                                   const float* __restrict__ fw,
                                                   unsigned short* __restrict__ qb,
                                                   unsigned short* __restrict__ kb,
                                                   unsigned short* __restrict__ vb) {
    const int n = blockIdx.x;
    const int tid = threadIdx.x, wave = tid >> 6, lane = tid & 63;
    const int t_i = n / 225, rem = n % 225, h_i = rem / 15, w_i = rem % 15;
    const float att_scale = 0.08838834764831845f * 1.4426950408889634f;  // 1/sqrt(128)*log2e

    float2 qv[3], kv[3], vv[3];
    float sq = 0.f, sk = 0.f;
#pragma unroll
    for (int c = 0; c < 3; c++) {
        int p = tid + 256 * c;
        qv[c] = *(const float2*)(Qf + (size_t)n * DMODEL + 2 * p);
        kv[c] = *(const float2*)(Kf + (size_t)n * DMODEL + 2 * p);
        vv[c] = *(const float2*)(Vf + (size_t)n * DMODEL + 2 * p);
        sq += qv[c].x * qv[c].x + qv[c].y * qv[c].y;
        sk += kv[c].x * kv[c].x + kv[c].y * kv[c].y;
    }
#pragma unroll
    for (int off = 32; off >= 1; off >>= 1) {
        sq += __shfl_xor(sq, off, 64);
        sk += __shfl_xor(sk, off, 64);
    }
    __shared__ float red[2][4];
    if (lane == 0) { red[0][wave] = sq; red[1][wave] = sk; }
    __syncthreads();
    sq = red[0][0] + red[0][1] + red[0][2] + red[0][3];
    sk = red[1][0] + red[1][1] + red[1][2] + red[1][3];
    const float rq = rsqrtf(sq * (1.f / 1536.f) + 1e-6f) * att_scale;
    const float rk = rsqrtf(sk * (1.f / 1536.f) + 1e-6f);

#pragma unroll
    for (int c = 0; c < 3; c++) {
        int p = tid + 256 * c;
        int hd = p >> 6, pl = p & 63, dd = 2 * pl;
        float cs, sn;
        if (pl < 22)      { cs = ft[t_i * 44 + 2 * pl];        sn = ft[t_i * 44 + 2 * pl + 1]; }
        else if (pl < 43) { int pp = pl - 22; cs = fh[h_i * 42 + 2 * pp]; sn = fh[h_i * 42 + 2 * pp + 1]; }
        else              { int pp = pl - 43; cs = fw[w_i * 42 + 2 * pp]; sn = fw[w_i * 42 + 2 * pp + 1]; }
        int hidx = hd * 128 + dd;
        float q0 = qv[c].x * rq * qsc[hidx], q1 = qv[c].y * rq * qsc[hidx + 1];
        float k0 = kv[c].x * rk * ksc[hidx], k1 = kv[c].y * rk * ksc[hidx + 1];
        size_t o = ((size_t)hd * N_TOK + n) * HDIM + dd;
        unsigned qo = (unsigned)f2bf(q0 * cs - q1 * sn) | ((unsigned)f2bf(q0 * sn + q1 * cs) << 16);
        unsigned ko = (unsigned)f2bf(k0 * cs - k1 * sn) | ((unsigned)f2bf(k0 * sn + k1 * cs) << 16);
        unsigned vo = (unsigned)f2bf(vv[c].x) | ((unsigned)f2bf(vv[c].y) << 16);
        *(unsigned*)(qb + o) = qo;
        *(unsigned*)(kb + o) = ko;
        *(unsigned*)(vb + o) = vo;
    }
}

// ----------------- transpose V: [head][tok][128] -> [head][128][VT_STRIDE] bf16
// Pad columns [N_TOK, VT_STRIDE) are WRITTEN AS ZERO (recycled region NaN hazard).
__global__ __launch_bounds__(256) void k_transpose_v(const unsigned short* __restrict__ vbi,
                                                     unsigned short* __restrict__ vt) {
    __shared__ unsigned short tile[32][33];
    const int head = blockIdx.z;
    const int t0 = blockIdx.x * 32, d0 = blockIdx.y * 32;
    const int tx = threadIdx.x, ty = threadIdx.y;      // 32 x 8
#pragma unroll
    for (int i = 0; i < 4; i++) {
        int t = t0 + ty + 8 * i;
        tile[ty + 8 * i][tx] = (t < N_TOK) ? vbi[((size_t)head * N_TOK + t) * HDIM + d0 + tx] : 0;
    }
    __syncthreads();
    int t = t0 + tx;                                   // < VT_STRIDE always
#pragma unroll
    for (int i = 0; i < 4; i++)
        vt[((size_t)head * HDIM + d0 + ty + 8 * i) * VT_STRIDE + t] = tile[tx][ty + 8 * i];
}

// ------------------------- split-KV flash attention, async-staged tiles (R5)
// Block = (q-tile 64 rows, head, split). 4 waves x 16 rows each. KV tiles of 64.
// exp2-domain softmax (log2e folded into q).
//
// LDS tiles are LINEAR (global_load_lds dest must be base+lane*16); bank
// conflicts are avoided by the both-sides XOR swizzle (rule #21):
//   16B chunk s stored at  s = (c & ~7) | ((c & 7) ^ (row & 7))
// applied to the per-lane GLOBAL source address at stage time and to the
// ds_read address at use time (involution).  All b128 reads then hit the
// 8-cycle wave64 minimum.  P uses the same swizzle (write scalar, read b128).
// LDS total = 16384 (K) + 16384 (V^T) + 8192 (P) = 40960 -> 4 blocks/CU.
__global__ __launch_bounds__(256, 4) void k_attn_part(const unsigned short* __restrict__ qb,
                                                      const unsigned short* __restrict__ kb,
                                                      const unsigned short* __restrict__ vt,
                                                      float* __restrict__ Opart,
                                                      float* __restrict__ mbuf,
                                                      float* __restrict__ lbuf) {
    __shared__ __align__(16) unsigned short Ks[64 * 128];   // [key][d]   linear+swz
    __shared__ __align__(16) unsigned short Vs[128 * 64];   // [d][key]   linear+swz
    __shared__ __align__(16) unsigned short Ps[4][16 * 64]; // per-wave P [qrow][key] swz

    const int tid = threadIdx.x, wave = tid >> 6, lane = tid & 63;
    const int quad = lane >> 4, l16 = lane & 15, x7 = l16 & 7;
    const int head = blockIdx.y, z = blockIdx.z;
    const int q0 = blockIdx.x * 64 + wave * 16;
    const unsigned short* qh = qb + (size_t)head * N_TOK * HDIM;
    const unsigned short* kh = kb + (size_t)head * N_TOK * HDIM;
    const unsigned short* vh = vt + (size_t)head * HDIM * VT_STRIDE;
    unsigned short* ps = Ps[wave];

    const int kbeg = z ? KSPLIT : 0;
    const int kend = z ? N_TOK : KSPLIT;

    // swizzled 16B-chunk read offsets (in shorts); chunk c = ks*4+quad, row&7 = l16&7.
    // Shared by Ks (ks=0..3), Vs and Ps (ks=0..1) reads.
    int koff[4];
#pragma unroll
    for (int ks = 0; ks < 4; ks++) {
        int c = ks * 4 + quad;
        koff[ks] = ((c & 8) | ((c & 7) ^ x7)) * 8;
    }

    // staging: thread covers LDS chunk (tid + 256*i), i=0..3 (lane-linear dest).
    // K:  chunk = row*16 + s  (row = krow+16i, s = tid&15), source col c = swz(s,row&7)
    // V^T: chunk = d*8 + s    (d = vd+32i,  s = tid&7),    source col c = s ^ (d&7)
    const int krow = tid >> 4, ksw = tid & 15;
    const int kc = (ksw & 8) | ((ksw & 7) ^ (krow & 7));   // (krow+16i)&7 == krow&7
    const int vd = tid >> 3, vsw = tid & 7;
    const int vc = vsw ^ (vd & 7);                          // (vd+32i)&7 == vd&7
    const unsigned short* ksrc = kh + (size_t)krow * HDIM + kc * 8;
    const unsigned short* vsrc = vh + (size_t)vd * VT_STRIDE + vc * 8;

    // Q fragments (A-layout: lane row l16, k = ks*32+quad*8..+7), loaded once
    bf16x8 aq[4];
    {
        int qrow = q0 + l16;
        if (qrow < N_TOK) {
#pragma unroll
            for (int ks = 0; ks < 4; ks++)
                aq[ks] = *(const bf16x8*)&qh[(size_t)qrow * HDIM + ks * 32 + quad * 8];
        } else {
#pragma unroll
            for (int ks = 0; ks < 4; ks++) aq[ks] = (bf16x8)(__bf16)0.0f;
        }
    }

    floatx4 oacc[8] = {};
    float m_r[4] = {-1e30f, -1e30f, -1e30f, -1e30f};
    float l_r[4] = {0.f, 0.f, 0.f, 0.f};   // per-lane PARTIAL sums (reduced at end)

    for (int kb0 = kbeg; kb0 < kend; kb0 += 64) {
        const bool fullt = (kb0 + 64 <= kend);   // false only on last tile of z=1

        // ---- async stage K (64x128) and V^T (128x64), source-preswizzled
        if (fullt) {
#pragma unroll
            for (int i = 0; i < 4; i++)
                gload_lds16(ksrc + (size_t)(kb0 + 16 * i) * HDIM, &Ks[(tid + 256 * i) * 8]);
        } else {
#pragma unroll
            for (int i = 0; i < 4; i++) {
                int gk = kb0 + krow + 16 * i;
                gk = gk < N_TOK ? gk : N_TOK - 1;          // clamp; masked in softmax
                gload_lds16(kh + (size_t)gk * HDIM + kc * 8, &Ks[(tid + 256 * i) * 8]);
            }
        }
#pragma unroll
        for (int i = 0; i < 4; i++)   // kb0+63 <= 2943 < VT_STRIDE, pad zeroed
            gload_lds16(vsrc + (size_t)(32 * i) * VT_STRIDE + kb0, &Vs[(tid + 256 * i) * 8]);
        __syncthreads();   // drains vmcnt before barrier

        // ---- S = Q K^T for this wave's 16 rows x 64 keys
        floatx4 sa[4] = {};
#pragma unroll
        for (int j = 0; j < 4; j++)
#pragma unroll
            for (int ks = 0; ks < 4; ks++) {
                bf16x8 bkf = *(const bf16x8*)&Ks[(j * 16 + l16) * HDIM + koff[ks]];
                sa[j] = MFMA(aq[ks], bkf, sa[j]);
            }

        // ---- row max (fast path: no masking on full tiles)
        float xm[4];
        bool valid[4];
        if (fullt) {
#pragma unroll
            for (int r = 0; r < 4; r++)
                xm[r] = fmaxf(fmaxf(sa[0][r], sa[1][r]), fmaxf(sa[2][r], sa[3][r]));
        } else {
#pragma unroll
            for (int j = 0; j < 4; j++) valid[j] = (kb0 + j * 16 + l16) < kend;
#pragma unroll
            for (int r = 0; r < 4; r++) {
                float x = -1e30f;
#pragma unroll
                for (int j = 0; j < 4; j++) x = fmaxf(x, valid[j] ? sa[j][r] : -1e30f);
                xm[r] = x;
            }
        }
#pragma unroll
        for (int r = 0; r < 4; r++)
#pragma unroll
            for (int off = 8; off >= 1; off >>= 1)
                xm[r] = fmaxf(xm[r], __shfl_xor(xm[r], off, 16));

        // ---- defer-max (T13, THR=8 in exp2 domain): skip rescale unless needed
        bool need = false;
#pragma unroll
        for (int r = 0; r < 4; r++) need |= (xm[r] > m_r[r] + 8.f);
        if (__any(need)) {
#pragma unroll
            for (int r = 0; r < 4; r++) {
                float mn = fmaxf(m_r[r], xm[r]);
                float a = exp2f(m_r[r] - mn);   // first tile: exp2(-inf)=0
                m_r[r] = mn;
                l_r[r] *= a;
#pragma unroll
                for (int jd = 0; jd < 8; jd++) oacc[jd][r] *= a;
            }
        }

        // ---- P = exp2(S - m), bf16 into swizzled per-wave LDS; partial row sums
        float rsum[4] = {0.f, 0.f, 0.f, 0.f};
        const int phi = l16 >> 3;
        const int pq4 = (quad & 1) * 4;
        if (fullt) {
#pragma unroll
            for (int j = 0; j < 4; j++)
#pragma unroll
                for (int r = 0; r < 4; r++) {
                    float p = exp2f(sa[j][r] - m_r[r]);
                    rsum[r] += p;
                    ps[(quad * 4 + r) * 64 + (((j * 2 + phi) ^ (pq4 + r)) << 3) + x7] =
                        __builtin_bit_cast(unsigned short, (__bf16)p);
                }
        } else {
#pragma unroll
            for (int j = 0; j < 4; j++)
#pragma unroll
                for (int r = 0; r < 4; r++) {
                    float p = valid[j] ? exp2f(sa[j][r] - m_r[r]) : 0.f;
                    rsum[r] += p;
                    ps[(quad * 4 + r) * 64 + (((j * 2 + phi) ^ (pq4 + r)) << 3) + x7] =
                        __builtin_bit_cast(unsigned short, (__bf16)p);
                }
        }
#pragma unroll
        for (int r = 0; r < 4; r++) l_r[r] += rsum[r];

        // ---- O += P V  (P from per-wave LDS; V^T frags from LDS, both swz reads)
#pragma unroll
        for (int ks = 0; ks < 2; ks++) {
            bf16x8 ap = *(const bf16x8*)&ps[l16 * 64 + koff[ks]];
#pragma unroll
            for (int jd = 0; jd < 8; jd++) {
                bf16x8 bvf = *(const bf16x8*)&Vs[(jd * 16 + l16) * 64 + koff[ks]];
                oacc[jd] = MFMA(ap, bvf, oacc[jd]);
            }
        }
        __syncthreads();
    }

    // ---- reduce l partials across the 16-lane group (hoisted out of k-loop)
#pragma unroll
    for (int r = 0; r < 4; r++)
#pragma unroll
        for (int off = 8; off >= 1; off >>= 1)
            l_r[r] += __shfl_xor(l_r[r], off, 16);

    // ---- store un-normalized O + (m,l)
#pragma unroll
    for (int r = 0; r < 4; r++) {
        int rg = q0 + quad * 4 + r;
        if (rg < N_TOK) {
            size_t rbase = ((size_t)(z * NHEAD + head) * N_TOK + rg) * HDIM;
#pragma unroll
            for (int jd = 0; jd < 8; jd++)
                Opart[rbase + jd * 16 + l16] = oacc[jd][r];
            if (l16 == 0) {
                int mi = (z * NHEAD + head) * N_TOK + rg;
                mbuf[mi] = m_r[r];
                lbuf[mi] = l_r[r];
            }
        }
    }
}

// ----------------------------------------------- combine the two KV splits
__global__ __launch_bounds__(256) void k_combine(const float* __restrict__ Opart,
                                                 const float* __restrict__ mbuf,
                                                 const float* __restrict__ lbuf,
                                                 unsigned short* __restrict__ ab) {
    const int R = NHEAD * N_TOK;
    int r = blockIdx.x * 8 + (threadIdx.x >> 5);
    if (r >= R) return;
    int l32 = threadIdx.x & 31;
    float m0 = mbuf[r], m1 = mbuf[R + r];
    float l0 = lbuf[r], l1 = lbuf[R + r];
    float m = fmaxf(m0, m1);
    float w0 = exp2f(m0 - m), w1 = exp2f(m1 - m);
    float inv = 1.f / (l0 * w0 + l1 * w1);
    w0 *= inv; w1 *= inv;
    float4 a = *(const float4*)&Opart[(size_t)r * HDIM + l32 * 4];
    float4 b = *(const float4*)&Opart[((size_t)R + r) * HDIM + l32 * 4];
    int head = r / N_TOK, tok = r % N_TOK;
    unsigned short* o = ab + (size_t)tok * DMODEL + head * HDIM + l32 * 4;
    uint2 pk;
    pk.x = (unsigned)f2bf(a.x * w0 + b.x * w1) | ((unsigned)f2bf(a.y * w0 + b.y * w1) << 16);
    pk.y = (unsigned)f2bf(a.z * w0 + b.z * w1) | ((unsigned)f2bf(a.w * w0 + b.w * w1) << 16);
    *(uint2*)o = pk;
}

// ---------------------------------------------------------------------------
extern "C" void kernel_launch(void* const* d_in, const int* in_sizes, int n_in,
                              void* d_out, int out_size, void* d_ws, size_t ws_size,
                              hipStream_t stream) {
    const float* x   = (const float*)d_in[0];
    const float* Wq  = (const float*)d_in[1];
    const float* bq  = (const float*)d_in[2];
    const float* Wk  = (const float*)d_in[3];
    const float* bk  = (const float*)d_in[4];
    const float* Wv  = (const float*)d_in[5];
    const float* bv  = (const float*)d_in[6];
    const float* Wo  = (const float*)d_in[7];
    const float* bo  = (const float*)d_in[8];
    const float* qsc = (const float*)d_in[9];
    const float* ksc = (const float*)d_in[10];
    const float* ft  = (const float*)d_in[11];
    const float* fh  = (const float*)d_in[12];
    const float* fw  = (const float*)d_in[13];

    // Layout note: ab sits BEFORE the fp32 region so the O-GEMM's A-tile
    // over-reads (rows 2925..2943) land inside d_ws, never past its end.
    char* ws = (char*)d_ws;
    unsigned short* xb   = (unsigned short*)ws; ws += (size_t)N_TOK * DMODEL * 2;          // 8,985,600
    unsigned short* Wt   = (unsigned short*)ws; ws += (size_t)4 * DMODEL * DMODEL * 2;     // 18,874,368
    unsigned short* ab   = (unsigned short*)ws; ws += (size_t)N_TOK * DMODEL * 2;          // 8,985,600
    char* qkvf_region    = ws;                  ws += (size_t)3 * N_TOK * DMODEL * 4;      // 53,913,600
    unsigned short* qkvb = (unsigned short*)ws; ws += (size_t)3 * N_TOK * DMODEL * 2;      // 26,956,800

    // Phase 1: qkvf_region holds fp32 QKV projections (53.9 MB).
    float* Qf = (float*)qkvf_region;
    float* Kf = Qf + (size_t)N_TOK * DMODEL;
    float* Vf = Qf + (size_t)2 * N_TOK * DMODEL;
    // Phase 2 (after k_norm_rope): Opart 35.9MB | m/l 0.56MB | vt 9.04MB = 45.5MB.
    float* Opart = (float*)qkvf_region;
    float* mbuf  = Opart + (size_t)2 * NHEAD * N_TOK * HDIM;
    float* lbuf  = mbuf + (size_t)2 * NHEAD * N_TOK;
    unsigned short* vtp = (unsigned short*)(lbuf + (size_t)2 * NHEAD * N_TOK);

    unsigned short* qbp = qkvb;
    unsigned short* kbp = qkvb + (size_t)N_TOK * DMODEL;
    unsigned short* vbp = qkvb + (size_t)2 * N_TOK * DMODEL;

    const int nelem = N_TOK * DMODEL;
    k_convert_x<<<(nelem / 4 + 255) / 256, 256, 0, stream>>>(x, xb, nelem);
    k_transpose_w<<<dim3(48, 48, 4), dim3(32, 8), 0, stream>>>(Wq, Wk, Wv, Wo, Wt);
    k_gemm<<<dim3(12, 23, 3), 256, 0, stream>>>(xb, Wt, bq, bk, bv, Qf, N_TOK);
    k_norm_rope<<<N_TOK, 256, 0, stream>>>(Qf, Kf, Vf, qsc, ksc, ft, fh, fw, qbp, kbp, vbp);
    k_transpose_v<<<dim3(92, 4, NHEAD), dim3(32, 8), 0, stream>>>(vbp, vtp);
    k_attn_part<<<dim3(46, NHEAD, 2), 256, 0, stream>>>(qbp, kbp, vtp, Opart, mbuf, lbuf);
    k_combine<<<(NHEAD * N_TOK + 7) / 8, 256, 0, stream>>>(Opart, mbuf, lbuf, ab);
    k_gemm<<<dim3(12, 23, 1), 256, 0, stream>>>(ab, Wt + (size_t)3 * DMODEL * DMODEL,
                                                bo, bo, bo, (float*)d_out, N_TOK);
}

// Round 3
// 368.684 us; speedup vs baseline: 1.1442x; 1.0713x over previous
//
#include <hip/hip_runtime.h>

// ---------------------------------------------------------------------------
// MultiHeadAttention (B=1, N=2925, D_MODEL=1536, 12 heads x 128) on gfx950.
// convert/transpose -> fused QKV bf16-MFMA GEMM (global_load_lds staging) ->
// RMSNorm+3D RoPE (exp2-domain q-scale) -> V transpose -> split-KV flash
// attention (swapped-QK^T, lane-local P, defer-max) -> combine -> O GEMM.
// ---------------------------------------------------------------------------

#define N_TOK 2925
#define DMODEL 1536
#define NHEAD 12
#define HDIM 128
#define KSPLIT 1472           // split-KV boundary (23 tiles of 64)
#define VT_STRIDE 2944        // N_TOK padded to x64; pad MUST be zeroed (NaN hazard)

typedef __attribute__((ext_vector_type(8))) __bf16 bf16x8;
typedef __attribute__((ext_vector_type(4))) float floatx4;

#define MFMA(a, b, c) __builtin_amdgcn_mfma_f32_16x16x32_bf16((a), (b), (c), 0, 0, 0)

static __device__ __forceinline__ unsigned short f2bf(float f) {
    unsigned u = __builtin_bit_cast(unsigned, f);
    return (unsigned short)((u + 0x7fffu + ((u >> 16) & 1u)) >> 16);
}

// async global->LDS 16B/lane (emits global_load_lds_dwordx4).
// LDS dest MUST be wave-uniform-base + lane*16.
static __device__ __forceinline__ void gload_lds16(const unsigned short* g, unsigned short* l) {
    __builtin_amdgcn_global_load_lds((const __attribute__((address_space(1))) void*)g,
                                     (__attribute__((address_space(3))) void*)l, 16, 0, 0);
}

// ---------------------------------------------------------------- convert x
__global__ __launch_bounds__(256) void k_convert_x(const float* __restrict__ x,
                                                   unsigned short* __restrict__ xb, int n) {
    int i = (blockIdx.x * 256 + threadIdx.x) * 4;
    if (i < n) {
        float4 v = *(const float4*)(x + i);
        uint2 o;
        o.x = (unsigned)f2bf(v.x) | ((unsigned)f2bf(v.y) << 16);
        o.y = (unsigned)f2bf(v.z) | ((unsigned)f2bf(v.w) << 16);
        *(uint2*)(xb + i) = o;
    }
}

// ---------------------------------------------- transpose W [k][n] -> Wt [n][k] bf16
__global__ __launch_bounds__(256) void k_transpose_w(const float* __restrict__ W0,
                                                     const float* __restrict__ W1,
                                                     const float* __restrict__ W2,
                                                     const float* __restrict__ W3,
                                                     unsigned short* __restrict__ Wt) {
    __shared__ float tile[32][33];
    const float* W = blockIdx.z == 0 ? W0 : blockIdx.z == 1 ? W1 : blockIdx.z == 2 ? W2 : W3;
    unsigned short* out = Wt + (size_t)blockIdx.z * DMODEL * DMODEL;
    int tx = threadIdx.x, ty = threadIdx.y;           // 32 x 8
    int bx = blockIdx.x * 32, by = blockIdx.y * 32;
#pragma unroll
    for (int i = 0; i < 4; i++)
        tile[ty + 8 * i][tx] = W[(size_t)(by + ty + 8 * i) * DMODEL + bx + tx];
    __syncthreads();
#pragma unroll
    for (int i = 0; i < 4; i++)
        out[(size_t)(bx + ty + 8 * i) * DMODEL + by + tx] = f2bf(tile[tx][ty + 8 * i]);
}

// ------------------------------------------------------------ bf16 MFMA GEMM
// m97 structure: unpadded stride-32 LDS tiles staged via global_load_lds(16B).
__global__ __launch_bounds__(256, 2) void k_gemm(const unsigned short* __restrict__ A,
                                                 const unsigned short* __restrict__ BtBase,
                                                 const float* __restrict__ b0,
                                                 const float* __restrict__ b1,
                                                 const float* __restrict__ b2,
                                                 float* __restrict__ Cbase, int M) {
    const int z = blockIdx.z;
    const unsigned short* Bt = BtBase + (size_t)z * DMODEL * DMODEL;
    const float* bias = (z == 0) ? b0 : (z == 1) ? b1 : b2;
    float* C = Cbase + (size_t)z * M * DMODEL;

    __shared__ __align__(16) unsigned short As[128 * 32];   // [row][k], contiguous
    __shared__ __align__(16) unsigned short Bs[128 * 32];   // [n][k],   contiguous

    const int tid = threadIdx.x;
    const int wave = tid >> 6, lane = tid & 63, quad = lane >> 4, l16 = lane & 15;
    const int wr = wave >> 1, wc = wave & 1;
    const int m0 = blockIdx.y * 128, n0 = blockIdx.x * 128;

    // staging coords: thread covers row r4 (+64 on 2nd issue), 16B col chunk c4
    const int r4 = tid >> 2, c4 = (tid & 3) * 8;
    // NOTE: A rows m0+r4(+64) may exceed M (max 2943 > 2924): reads land in the
    // next ws region (no fault); garbage only reaches acc rows discarded by rg<M.

    floatx4 acc[4][4] = {};

    for (int k0 = 0; k0 < DMODEL; k0 += 32) {
        gload_lds16(A + (size_t)(m0 + r4) * DMODEL + k0 + c4,       &As[r4 * 32 + c4]);
        gload_lds16(A + (size_t)(m0 + r4 + 64) * DMODEL + k0 + c4,  &As[(r4 + 64) * 32 + c4]);
        gload_lds16(Bt + (size_t)(n0 + r4) * DMODEL + k0 + c4,      &Bs[r4 * 32 + c4]);
        gload_lds16(Bt + (size_t)(n0 + r4 + 64) * DMODEL + k0 + c4, &Bs[(r4 + 64) * 32 + c4]);
        __syncthreads();

        bf16x8 af[4], bfm[4];
#pragma unroll
        for (int i = 0; i < 4; i++)
            af[i] = *(const bf16x8*)&As[(wr * 64 + i * 16 + l16) * 32 + quad * 8];
#pragma unroll
        for (int j = 0; j < 4; j++)
            bfm[j] = *(const bf16x8*)&Bs[(wc * 64 + j * 16 + l16) * 32 + quad * 8];
#pragma unroll
        for (int i = 0; i < 4; i++)
#pragma unroll
            for (int j = 0; j < 4; j++)
                acc[i][j] = MFMA(af[i], bfm[j], acc[i][j]);
        __syncthreads();
    }

#pragma unroll
    for (int j = 0; j < 4; j++) {
        int cg = n0 + wc * 64 + j * 16 + l16;
        float bv = bias[cg];
#pragma unroll
        for (int i = 0; i < 4; i++) {
            int rbase = m0 + wr * 64 + i * 16 + quad * 4;
#pragma unroll
            for (int r = 0; r < 4; r++) {
                int rg = rbase + r;
                if (rg < M) C[(size_t)rg * DMODEL + cg] = acc[i][j][r] + bv;
            }
        }
    }
}

// ---------------------------------- fused RMSNorm (full 1536) + 3D RoPE + pack
// q pre-scaled by (1/sqrt(HDIM))*log2(e) -> softmax runs in exp2 domain.
__global__ __launch_bounds__(256) void k_norm_rope(const float* __restrict__ Qf,
                                                   const float* __restrict__ Kf,
                                                   const float* __restrict__ Vf,
                                                   const float* __restrict__ qsc,
                                                   const float* __restrict__ ksc,
                                                   const float* __restrict__ ft,
                                                   const float* __restrict__ fh,
                                                   const float* __restrict__ fw,
                                                   unsigned short* __restrict__ qb,
                                                   unsigned short* __restrict__ kb,
                                                   unsigned short* __restrict__ vb) {
    const int n = blockIdx.x;
    const int tid = threadIdx.x, wave = tid >> 6, lane = tid & 63;
    const int t_i = n / 225, rem = n % 225, h_i = rem / 15, w_i = rem % 15;
    const float att_scale = 0.08838834764831845f * 1.4426950408889634f;  // 1/sqrt(128)*log2e

    float2 qv[3], kv[3], vv[3];
    float sq = 0.f, sk = 0.f;
#pragma unroll
    for (int c = 0; c < 3; c++) {
        int p = tid + 256 * c;
        qv[c] = *(const float2*)(Qf + (size_t)n * DMODEL + 2 * p);
        kv[c] = *(const float2*)(Kf + (size_t)n * DMODEL + 2 * p);
        vv[c] = *(const float2*)(Vf + (size_t)n * DMODEL + 2 * p);
        sq += qv[c].x * qv[c].x + qv[c].y * qv[c].y;
        sk += kv[c].x * kv[c].x + kv[c].y * kv[c].y;
    }
#pragma unroll
    for (int off = 32; off >= 1; off >>= 1) {
        sq += __shfl_xor(sq, off, 64);
        sk += __shfl_xor(sk, off, 64);
    }
    __shared__ float red[2][4];
    if (lane == 0) { red[0][wave] = sq; red[1][wave] = sk; }
    __syncthreads();
    sq = red[0][0] + red[0][1] + red[0][2] + red[0][3];
    sk = red[1][0] + red[1][1] + red[1][2] + red[1][3];
    const float rq = rsqrtf(sq * (1.f / 1536.f) + 1e-6f) * att_scale;
    const float rk = rsqrtf(sk * (1.f / 1536.f) + 1e-6f);

#pragma unroll
    for (int c = 0; c < 3; c++) {
        int p = tid + 256 * c;
        int hd = p >> 6, pl = p & 63, dd = 2 * pl;
        float cs, sn;
        if (pl < 22)      { cs = ft[t_i * 44 + 2 * pl];        sn = ft[t_i * 44 + 2 * pl + 1]; }
        else if (pl < 43) { int pp = pl - 22; cs = fh[h_i * 42 + 2 * pp]; sn = fh[h_i * 42 + 2 * pp + 1]; }
        else              { int pp = pl - 43; cs = fw[w_i * 42 + 2 * pp]; sn = fw[w_i * 42 + 2 * pp + 1]; }
        int hidx = hd * 128 + dd;
        float q0 = qv[c].x * rq * qsc[hidx], q1 = qv[c].y * rq * qsc[hidx + 1];
        float k0 = kv[c].x * rk * ksc[hidx], k1 = kv[c].y * rk * ksc[hidx + 1];
        size_t o = ((size_t)hd * N_TOK + n) * HDIM + dd;
        unsigned qo = (unsigned)f2bf(q0 * cs - q1 * sn) | ((unsigned)f2bf(q0 * sn + q1 * cs) << 16);
        unsigned ko = (unsigned)f2bf(k0 * cs - k1 * sn) | ((unsigned)f2bf(k0 * sn + k1 * cs) << 16);
        unsigned vo = (unsigned)f2bf(vv[c].x) | ((unsigned)f2bf(vv[c].y) << 16);
        *(unsigned*)(qb + o) = qo;
        *(unsigned*)(kb + o) = ko;
        *(unsigned*)(vb + o) = vo;
    }
}

// ----------------- transpose V: [head][tok][128] -> [head][128][VT_STRIDE] bf16
// Pad columns [N_TOK, VT_STRIDE) are WRITTEN AS ZERO (recycled region NaN hazard).
__global__ __launch_bounds__(256) void k_transpose_v(const unsigned short* __restrict__ vbi,
                                                     unsigned short* __restrict__ vt) {
    __shared__ unsigned short tile[32][33];
    const int head = blockIdx.z;
    const int t0 = blockIdx.x * 32, d0 = blockIdx.y * 32;
    const int tx = threadIdx.x, ty = threadIdx.y;      // 32 x 8
#pragma unroll
    for (int i = 0; i < 4; i++) {
        int t = t0 + ty + 8 * i;
        tile[ty + 8 * i][tx] = (t < N_TOK) ? vbi[((size_t)head * N_TOK + t) * HDIM + d0 + tx] : 0;
    }
    __syncthreads();
    int t = t0 + tx;                                   // < VT_STRIDE always
#pragma unroll
    for (int i = 0; i < 4; i++)
        vt[((size_t)head * HDIM + d0 + ty + 8 * i) * VT_STRIDE + t] = tile[tx][ty + 8 * i];
}

// ------------------- split-KV flash attention, swapped-QK^T structure (R6)
// Block = (q-tile 64 rows, head, split). 4 waves x 16 rows each. KV tiles of 64.
// exp2-domain softmax (log2e folded into q).
//
// S^T = MFMA(K, Q): sa[j][r] = S[qrow=l16][key = j*16 + quad*4 + r].
// Each lane owns ONE q-row (l16): row-max/sum are 15 in-lane fmax + 2 quad
// shuffles; P is packed to bf16 pairs and stored with 4 conflict-free
// ds_write_b64 (banks = 16 disjoint pairs x 4 lanes = wave64-b64 minimum).
// K/V^T/P ds_read_b128 use the both-sides XOR swizzle (rule #21):
//   16B chunk s stored at  s = (c & ~7) | ((c & 7) ^ (row & 7))
// pre-applied to the per-lane GLOBAL source address at stage time.
// LDS total = 16384 (K) + 16384 (V^T) + 8192 (P) = 40960 -> 4 blocks/CU.
__global__ __launch_bounds__(256, 4) void k_attn_part(const unsigned short* __restrict__ qb,
                                                      const unsigned short* __restrict__ kb,
                                                      const unsigned short* __restrict__ vt,
                                                      float* __restrict__ Opart,
                                                      float* __restrict__ mbuf,
                                                      float* __restrict__ lbuf) {
    __shared__ __align__(16) unsigned short Ks[64 * 128];   // [key][d]   linear+swz
    __shared__ __align__(16) unsigned short Vs[128 * 64];   // [d][key]   linear+swz
    __shared__ __align__(16) unsigned short Ps[4][16 * 64]; // per-wave P [qrow][key] swz

    const int tid = threadIdx.x, wave = tid >> 6, lane = tid & 63;
    const int quad = lane >> 4, l16 = lane & 15, x7 = l16 & 7;
    const int head = blockIdx.y, z = blockIdx.z;
    const int q0 = blockIdx.x * 64 + wave * 16;
    const unsigned short* qh = qb + (size_t)head * N_TOK * HDIM;
    const unsigned short* kh = kb + (size_t)head * N_TOK * HDIM;
    const unsigned short* vh = vt + (size_t)head * HDIM * VT_STRIDE;
    unsigned short* ps = Ps[wave];

    const int kbeg = z ? KSPLIT : 0;
    const int kend = z ? N_TOK : KSPLIT;

    // swizzled 16B-chunk read offsets (in shorts); chunk c = ks*4+quad, row&7 = l16&7.
    // Shared by Ks (ks=0..3), Vs and Ps (ks=0..1) reads.
    int koff[4];
#pragma unroll
    for (int ks = 0; ks < 4; ks++) {
        int c = ks * 4 + quad;
        koff[ks] = ((c & 8) | ((c & 7) ^ x7)) * 8;
    }
    // P write base (shorts): row l16, chunk (j*2 + (quad>>1)) ^ x7, half (quad&1).
    const int pwq = (quad >> 1), pwh = (quad & 1) * 4;

    // staging: thread covers LDS chunk (tid + 256*i), i=0..3 (lane-linear dest).
    // K:  chunk = row*16 + s  (row = krow+16i, s = tid&15), source col c = swz(s,row&7)
    // V^T: chunk = d*8 + s    (d = vd+32i,  s = tid&7),    source col c = s ^ (d&7)
    const int krow = tid >> 4, ksw = tid & 15;
    const int kc = (ksw & 8) | ((ksw & 7) ^ (krow & 7));   // (krow+16i)&7 == krow&7
    const int vd = tid >> 3, vsw = tid & 7;
    const int vc = vsw ^ (vd & 7);                          // (vd+32i)&7 == vd&7
    const unsigned short* ksrc = kh + (size_t)krow * HDIM + kc * 8;
    const unsigned short* vsrc = vh + (size_t)vd * VT_STRIDE + vc * 8;

    // Q fragments (8 consecutive bf16 = 8 k's of row l16; used as the MFMA
    // B-operand so column n = q-row l16), loaded once.
    bf16x8 aq[4];
    {
        int qrow = q0 + l16;
        if (qrow < N_TOK) {
#pragma unroll
            for (int ks = 0; ks < 4; ks++)
                aq[ks] = *(const bf16x8*)&qh[(size_t)qrow * HDIM + ks * 32 + quad * 8];
        } else {
#pragma unroll
            for (int ks = 0; ks < 4; ks++) aq[ks] = (bf16x8)(__bf16)0.0f;
        }
    }

    floatx4 oacc[8] = {};
    float m_l = -1e30f;   // running max of lane's own q-row (l16)
    float l_l = 0.f;      // per-lane PARTIAL sum for q-row l16 (reduced over quads at end)

    for (int kb0 = kbeg; kb0 < kend; kb0 += 64) {
        const bool fullt = (kb0 + 64 <= kend);   // false only on last tile of z=1

        // ---- async stage K (64x128) and V^T (128x64), source-preswizzled
        if (fullt) {
#pragma unroll
            for (int i = 0; i < 4; i++)
                gload_lds16(ksrc + (size_t)(kb0 + 16 * i) * HDIM, &Ks[(tid + 256 * i) * 8]);
        } else {
#pragma unroll
            for (int i = 0; i < 4; i++) {
                int gk = kb0 + krow + 16 * i;
                gk = gk < N_TOK ? gk : N_TOK - 1;          // clamp; masked in softmax
                gload_lds16(kh + (size_t)gk * HDIM + kc * 8, &Ks[(tid + 256 * i) * 8]);
            }
        }
#pragma unroll
        for (int i = 0; i < 4; i++)   // kb0+63 <= 2943 < VT_STRIDE, pad zeroed
            gload_lds16(vsrc + (size_t)(32 * i) * VT_STRIDE + kb0, &Vs[(tid + 256 * i) * 8]);
        __syncthreads();   // drains vmcnt before barrier

        // ---- S^T = K Q^T : sa[j][r] = S[l16][kb0 + j*16 + quad*4 + r]
        floatx4 sa[4] = {};
#pragma unroll
        for (int j = 0; j < 4; j++)
#pragma unroll
            for (int ks = 0; ks < 4; ks++) {
                bf16x8 bkf = *(const bf16x8*)&Ks[(j * 16 + l16) * HDIM + koff[ks]];
                sa[j] = MFMA(bkf, aq[ks], sa[j]);
            }

        // ---- per-lane tile max over its 16 S values (own q-row), 2 quad shuffles
        float mt;
        if (fullt) {
            float m01 = fmaxf(fmaxf(sa[0][0], sa[0][1]), fmaxf(sa[0][2], sa[0][3]));
            float m23 = fmaxf(fmaxf(sa[1][0], sa[1][1]), fmaxf(sa[1][2], sa[1][3]));
            float m45 = fmaxf(fmaxf(sa[2][0], sa[2][1]), fmaxf(sa[2][2], sa[2][3]));
            float m67 = fmaxf(fmaxf(sa[3][0], sa[3][1]), fmaxf(sa[3][2], sa[3][3]));
            mt = fmaxf(fmaxf(m01, m23), fmaxf(m45, m67));
        } else {
            mt = -1e30f;
            const int kq = kb0 + quad * 4;
#pragma unroll
            for (int j = 0; j < 4; j++)
#pragma unroll
                for (int r = 0; r < 4; r++)
                    mt = fmaxf(mt, (kq + j * 16 + r < kend) ? sa[j][r] : -1e30f);
        }
        mt = fmaxf(mt, __shfl_xor(mt, 16));
        mt = fmaxf(mt, __shfl_xor(mt, 32));

        // ---- defer-max (T13, THR=8 in exp2 domain): skip rescale unless needed
        if (__any(mt > m_l + 8.f)) {
            float mn = fmaxf(m_l, mt);
            float alpha = exp2f(m_l - mn);   // first tile: exp2(-1e30-..)=0
            m_l = mn;
            l_l *= alpha;
#pragma unroll
            for (int r = 0; r < 4; r++) {
                float ar = __shfl(alpha, quad * 4 + r, 16);  // alpha of oacc row quad*4+r
#pragma unroll
                for (int jd = 0; jd < 8; jd++) oacc[jd][r] *= ar;
            }
        }

        // ---- P = exp2(S - m): 4 keys/lane/j, packed bf16 -> ds_write_b64
        if (fullt) {
#pragma unroll
            for (int j = 0; j < 4; j++) {
                float p0 = exp2f(sa[j][0] - m_l), p1 = exp2f(sa[j][1] - m_l);
                float p2 = exp2f(sa[j][2] - m_l), p3 = exp2f(sa[j][3] - m_l);
                l_l += (p0 + p1) + (p2 + p3);
                uint2 w;
                w.x = (unsigned)__builtin_bit_cast(unsigned short, (__bf16)p0) |
                      ((unsigned)__builtin_bit_cast(unsigned short, (__bf16)p1) << 16);
                w.y = (unsigned)__builtin_bit_cast(unsigned short, (__bf16)p2) |
                      ((unsigned)__builtin_bit_cast(unsigned short, (__bf16)p3) << 16);
                *(uint2*)&ps[l16 * 64 + (((j * 2 + pwq) ^ x7) << 3) + pwh] = w;
            }
        } else {
            const int kq = kb0 + quad * 4;
#pragma unroll
            for (int j = 0; j < 4; j++) {
                float p[4];
#pragma unroll
                for (int r = 0; r < 4; r++) {
                    p[r] = (kq + j * 16 + r < kend) ? exp2f(sa[j][r] - m_l) : 0.f;
                    l_l += p[r];
                }
                uint2 w;
                w.x = (unsigned)__builtin_bit_cast(unsigned short, (__bf16)p[0]) |
                      ((unsigned)__builtin_bit_cast(unsigned short, (__bf16)p[1]) << 16);
                w.y = (unsigned)__builtin_bit_cast(unsigned short, (__bf16)p[2]) |
                      ((unsigned)__builtin_bit_cast(unsigned short, (__bf16)p[3]) << 16);
                *(uint2*)&ps[l16 * 64 + (((j * 2 + pwq) ^ x7) << 3) + pwh] = w;
            }
        }

        // ---- O += P V  (P from per-wave LDS; V^T frags from LDS, both swz reads)
#pragma unroll
        for (int ks = 0; ks < 2; ks++) {
            bf16x8 ap = *(const bf16x8*)&ps[l16 * 64 + koff[ks]];
#pragma unroll
            for (int jd = 0; jd < 8; jd++) {
                bf16x8 bvf = *(const bf16x8*)&Vs[(jd * 16 + l16) * 64 + koff[ks]];
                oacc[jd] = MFMA(ap, bvf, oacc[jd]);
            }
        }
        __syncthreads();
    }

    // ---- reduce l partials across quads (lanes sharing l16)
    l_l += __shfl_xor(l_l, 16);
    l_l += __shfl_xor(l_l, 32);

    // ---- store un-normalized O + (m,l)
#pragma unroll
    for (int r = 0; r < 4; r++) {
        int rg = q0 + quad * 4 + r;
        if (rg < N_TOK) {
            size_t rbase = ((size_t)(z * NHEAD + head) * N_TOK + rg) * HDIM;
#pragma unroll
            for (int jd = 0; jd < 8; jd++)
                Opart[rbase + jd * 16 + l16] = oacc[jd][r];
        }
    }
    if (quad == 0 && q0 + l16 < N_TOK) {
        int mi = (z * NHEAD + head) * N_TOK + q0 + l16;
        mbuf[mi] = m_l;
        lbuf[mi] = l_l;
    }
}

// ----------------------------------------------- combine the two KV splits
__global__ __launch_bounds__(256) void k_combine(const float* __restrict__ Opart,
                                                 const float* __restrict__ mbuf,
                                                 const float* __restrict__ lbuf,
                                                 unsigned short* __restrict__ ab) {
    const int R = NHEAD * N_TOK;
    int r = blockIdx.x * 8 + (threadIdx.x >> 5);
    if (r >= R) return;
    int l32 = threadIdx.x & 31;
    float m0 = mbuf[r], m1 = mbuf[R + r];
    float l0 = lbuf[r], l1 = lbuf[R + r];
    float m = fmaxf(m0, m1);
    float w0 = exp2f(m0 - m), w1 = exp2f(m1 - m);
    float inv = 1.f / (l0 * w0 + l1 * w1);
    w0 *= inv; w1 *= inv;
    float4 a = *(const float4*)&Opart[(size_t)r * HDIM + l32 * 4];
    float4 b = *(const float4*)&Opart[((size_t)R + r) * HDIM + l32 * 4];
    int head = r / N_TOK, tok = r % N_TOK;
    unsigned short* o = ab + (size_t)tok * DMODEL + head * HDIM + l32 * 4;
    uint2 pk;
    pk.x = (unsigned)f2bf(a.x * w0 + b.x * w1) | ((unsigned)f2bf(a.y * w0 + b.y * w1) << 16);
    pk.y = (unsigned)f2bf(a.z * w0 + b.z * w1) | ((unsigned)f2bf(a.w * w0 + b.w * w1) << 16);
    *(uint2*)o = pk;
}

// ---------------------------------------------------------------------------
extern "C" void kernel_launch(void* const* d_in, const int* in_sizes, int n_in,
                              void* d_out, int out_size, void* d_ws, size_t ws_size,
                              hipStream_t stream) {
    const float* x   = (const float*)d_in[0];
    const float* Wq  = (const float*)d_in[1];
    const float* bq  = (const float*)d_in[2];
    const float* Wk  = (const float*)d_in[3];
    const float* bk  = (const float*)d_in[4];
    const float* Wv  = (const float*)d_in[5];
    const float* bv  = (const float*)d_in[6];
    const float* Wo  = (const float*)d_in[7];
    const float* bo  = (const float*)d_in[8];
    const float* qsc = (const float*)d_in[9];
    const float* ksc = (const float*)d_in[10];
    const float* ft  = (const float*)d_in[11];
    const float* fh  = (const float*)d_in[12];
    const float* fw  = (const float*)d_in[13];

    // Layout note: ab sits BEFORE the fp32 region so the O-GEMM's A-tile
    // over-reads (rows 2925..2943) land inside d_ws, never past its end.
    char* ws = (char*)d_ws;
    unsigned short* xb   = (unsigned short*)ws; ws += (size_t)N_TOK * DMODEL * 2;          // 8,985,600
    unsigned short* Wt   = (unsigned short*)ws; ws += (size_t)4 * DMODEL * DMODEL * 2;     // 18,874,368
    unsigned short* ab   = (unsigned short*)ws; ws += (size_t)N_TOK * DMODEL * 2;          // 8,985,600
    char* qkvf_region    = ws;                  ws += (size_t)3 * N_TOK * DMODEL * 4;      // 53,913,600
    unsigned short* qkvb = (unsigned short*)ws; ws += (size_t)3 * N_TOK * DMODEL * 2;      // 26,956,800

    // Phase 1: qkvf_region holds fp32 QKV projections (53.9 MB).
    float* Qf = (float*)qkvf_region;
    float* Kf = Qf + (size_t)N_TOK * DMODEL;
    float* Vf = Qf + (size_t)2 * N_TOK * DMODEL;
    // Phase 2 (after k_norm_rope): Opart 35.9MB | m/l 0.56MB | vt 9.04MB = 45.5MB.
    float* Opart = (float*)qkvf_region;
    float* mbuf  = Opart + (size_t)2 * NHEAD * N_TOK * HDIM;
    float* lbuf  = mbuf + (size_t)2 * NHEAD * N_TOK;
    unsigned short* vtp = (unsigned short*)(lbuf + (size_t)2 * NHEAD * N_TOK);

    unsigned short* qbp = qkvb;
    unsigned short* kbp = qkvb + (size_t)N_TOK * DMODEL;
    unsigned short* vbp = qkvb + (size_t)2 * N_TOK * DMODEL;

    const int nelem = N_TOK * DMODEL;
    k_convert_x<<<(nelem / 4 + 255) / 256, 256, 0, stream>>>(x, xb, nelem);
    k_transpose_w<<<dim3(48, 48, 4), dim3(32, 8), 0, stream>>>(Wq, Wk, Wv, Wo, Wt);
    k_gemm<<<dim3(12, 23, 3), 256, 0, stream>>>(xb, Wt, bq, bk, bv, Qf, N_TOK);
    k_norm_rope<<<N_TOK, 256, 0, stream>>>(Qf, Kf, Vf, qsc, ksc, ft, fh, fw, qbp, kbp, vbp);
    k_transpose_v<<<dim3(92, 4, NHEAD), dim3(32, 8), 0, stream>>>(vbp, vtp);
    k_attn_part<<<dim3(46, NHEAD, 2), 256, 0, stream>>>(qbp, kbp, vtp, Opart, mbuf, lbuf);
    k_combine<<<(NHEAD * N_TOK + 7) / 8, 256, 0, stream>>>(Opart, mbuf, lbuf, ab);
    k_gemm<<<dim3(12, 23, 1), 256, 0, stream>>>(ab, Wt + (size_t)3 * DMODEL * DMODEL,
                                                bo, bo, bo, (float*)d_out, N_TOK);
}

// Round 4
// 368.219 us; speedup vs baseline: 1.1456x; 1.0013x over previous
//
#include <hip/hip_runtime.h>

// ---------------------------------------------------------------------------
// MultiHeadAttention (B=1, N=2925, D_MODEL=1536, 12 heads x 128) on gfx950.
// convert/transpose -> fused QKV bf16-MFMA GEMM (global_load_lds staging) ->
// RMSNorm+3D RoPE (exp2-domain q-scale) -> V transpose -> split-KV flash
// attention (swapped-QK^T, phase-shifted async staging, counted vmcnt,
// raw barriers, XCD swizzle, setprio) -> combine -> O GEMM.
// ---------------------------------------------------------------------------

#define N_TOK 2925
#define DMODEL 1536
#define NHEAD 12
#define HDIM 128
#define KSPLIT 1472           // split-KV boundary (23 tiles of 64)
#define VT_STRIDE 2944        // N_TOK padded to x64; pad MUST be zeroed (NaN hazard)

typedef __attribute__((ext_vector_type(8))) __bf16 bf16x8;
typedef __attribute__((ext_vector_type(4))) float floatx4;

#define MFMA(a, b, c) __builtin_amdgcn_mfma_f32_16x16x32_bf16((a), (b), (c), 0, 0, 0)

static __device__ __forceinline__ unsigned short f2bf(float f) {
    unsigned u = __builtin_bit_cast(unsigned, f);
    return (unsigned short)((u + 0x7fffu + ((u >> 16) & 1u)) >> 16);
}

// async global->LDS 16B/lane (emits global_load_lds_dwordx4).
// LDS dest MUST be wave-uniform-base + lane*16.
static __device__ __forceinline__ void gload_lds16(const unsigned short* g, unsigned short* l) {
    __builtin_amdgcn_global_load_lds((const __attribute__((address_space(1))) void*)g,
                                     (__attribute__((address_space(3))) void*)l, 16, 0, 0);
}

// ---------------------------------------------------------------- convert x
__global__ __launch_bounds__(256) void k_convert_x(const float* __restrict__ x,
                                                   unsigned short* __restrict__ xb, int n) {
    int i = (blockIdx.x * 256 + threadIdx.x) * 4;
    if (i < n) {
        float4 v = *(const float4*)(x + i);
        uint2 o;
        o.x = (unsigned)f2bf(v.x) | ((unsigned)f2bf(v.y) << 16);
        o.y = (unsigned)f2bf(v.z) | ((unsigned)f2bf(v.w) << 16);
        *(uint2*)(xb + i) = o;
    }
}

// ---------------------------------------------- transpose W [k][n] -> Wt [n][k] bf16
__global__ __launch_bounds__(256) void k_transpose_w(const float* __restrict__ W0,
                                                     const float* __restrict__ W1,
                                                     const float* __restrict__ W2,
                                                     const float* __restrict__ W3,
                                                     unsigned short* __restrict__ Wt) {
    __shared__ float tile[32][33];
    const float* W = blockIdx.z == 0 ? W0 : blockIdx.z == 1 ? W1 : blockIdx.z == 2 ? W2 : W3;
    unsigned short* out = Wt + (size_t)blockIdx.z * DMODEL * DMODEL;
    int tx = threadIdx.x, ty = threadIdx.y;           // 32 x 8
    int bx = blockIdx.x * 32, by = blockIdx.y * 32;
#pragma unroll
    for (int i = 0; i < 4; i++)
        tile[ty + 8 * i][tx] = W[(size_t)(by + ty + 8 * i) * DMODEL + bx + tx];
    __syncthreads();
#pragma unroll
    for (int i = 0; i < 4; i++)
        out[(size_t)(bx + ty + 8 * i) * DMODEL + by + tx] = f2bf(tile[tx][ty + 8 * i]);
}

// ------------------------------------------------------------ bf16 MFMA GEMM
// m97 structure: unpadded stride-32 LDS tiles staged via global_load_lds(16B).
__global__ __launch_bounds__(256, 2) void k_gemm(const unsigned short* __restrict__ A,
                                                 const unsigned short* __restrict__ BtBase,
                                                 const float* __restrict__ b0,
                                                 const float* __restrict__ b1,
                                                 const float* __restrict__ b2,
                                                 float* __restrict__ Cbase, int M) {
    const int z = blockIdx.z;
    const unsigned short* Bt = BtBase + (size_t)z * DMODEL * DMODEL;
    const float* bias = (z == 0) ? b0 : (z == 1) ? b1 : b2;
    float* C = Cbase + (size_t)z * M * DMODEL;

    __shared__ __align__(16) unsigned short As[128 * 32];   // [row][k], contiguous
    __shared__ __align__(16) unsigned short Bs[128 * 32];   // [n][k],   contiguous

    const int tid = threadIdx.x;
    const int wave = tid >> 6, lane = tid & 63, quad = lane >> 4, l16 = lane & 15;
    const int wr = wave >> 1, wc = wave & 1;
    const int m0 = blockIdx.y * 128, n0 = blockIdx.x * 128;

    // staging coords: thread covers row r4 (+64 on 2nd issue), 16B col chunk c4
    const int r4 = tid >> 2, c4 = (tid & 3) * 8;
    // NOTE: A rows m0+r4(+64) may exceed M (max 2943 > 2924): reads land in the
    // next ws region (no fault); garbage only reaches acc rows discarded by rg<M.

    floatx4 acc[4][4] = {};

    for (int k0 = 0; k0 < DMODEL; k0 += 32) {
        gload_lds16(A + (size_t)(m0 + r4) * DMODEL + k0 + c4,       &As[r4 * 32 + c4]);
        gload_lds16(A + (size_t)(m0 + r4 + 64) * DMODEL + k0 + c4,  &As[(r4 + 64) * 32 + c4]);
        gload_lds16(Bt + (size_t)(n0 + r4) * DMODEL + k0 + c4,      &Bs[r4 * 32 + c4]);
        gload_lds16(Bt + (size_t)(n0 + r4 + 64) * DMODEL + k0 + c4, &Bs[(r4 + 64) * 32 + c4]);
        __syncthreads();

        bf16x8 af[4], bfm[4];
#pragma unroll
        for (int i = 0; i < 4; i++)
            af[i] = *(const bf16x8*)&As[(wr * 64 + i * 16 + l16) * 32 + quad * 8];
#pragma unroll
        for (int j = 0; j < 4; j++)
            bfm[j] = *(const bf16x8*)&Bs[(wc * 64 + j * 16 + l16) * 32 + quad * 8];
#pragma unroll
        for (int i = 0; i < 4; i++)
#pragma unroll
            for (int j = 0; j < 4; j++)
                acc[i][j] = MFMA(af[i], bfm[j], acc[i][j]);
        __syncthreads();
    }

#pragma unroll
    for (int j = 0; j < 4; j++) {
        int cg = n0 + wc * 64 + j * 16 + l16;
        float bv = bias[cg];
#pragma unroll
        for (int i = 0; i < 4; i++) {
            int rbase = m0 + wr * 64 + i * 16 + quad * 4;
#pragma unroll
            for (int r = 0; r < 4; r++) {
                int rg = rbase + r;
                if (rg < M) C[(size_t)rg * DMODEL + cg] = acc[i][j][r] + bv;
            }
        }
    }
}

// ---------------------------------- fused RMSNorm (full 1536) + 3D RoPE + pack
// q pre-scaled by (1/sqrt(HDIM))*log2(e) -> softmax runs in exp2 domain.
__global__ __launch_bounds__(256) void k_norm_rope(const float* __restrict__ Qf,
                                                   const float* __restrict__ Kf,
                                                   const float* __restrict__ Vf,
                                                   const float* __restrict__ qsc,
                                                   const float* __restrict__ ksc,
                                                   const float* __restrict__ ft,
                                                   const float* __restrict__ fh,
                                                   const float* __restrict__ fw,
                                                   unsigned short* __restrict__ qb,
                                                   unsigned short* __restrict__ kb,
                                                   unsigned short* __restrict__ vb) {
    const int n = blockIdx.x;
    const int tid = threadIdx.x, wave = tid >> 6, lane = tid & 63;
    const int t_i = n / 225, rem = n % 225, h_i = rem / 15, w_i = rem % 15;
    const float att_scale = 0.08838834764831845f * 1.4426950408889634f;  // 1/sqrt(128)*log2e

    float2 qv[3], kv[3], vv[3];
    float sq = 0.f, sk = 0.f;
#pragma unroll
    for (int c = 0; c < 3; c++) {
        int p = tid + 256 * c;
        qv[c] = *(const float2*)(Qf + (size_t)n * DMODEL + 2 * p);
        kv[c] = *(const float2*)(Kf + (size_t)n * DMODEL + 2 * p);
        vv[c] = *(const float2*)(Vf + (size_t)n * DMODEL + 2 * p);
        sq += qv[c].x * qv[c].x + qv[c].y * qv[c].y;
        sk += kv[c].x * kv[c].x + kv[c].y * kv[c].y;
    }
#pragma unroll
    for (int off = 32; off >= 1; off >>= 1) {
        sq += __shfl_xor(sq, off, 64);
        sk += __shfl_xor(sk, off, 64);
    }
    __shared__ float red[2][4];
    if (lane == 0) { red[0][wave] = sq; red[1][wave] = sk; }
    __syncthreads();
    sq = red[0][0] + red[0][1] + red[0][2] + red[0][3];
    sk = red[1][0] + red[1][1] + red[1][2] + red[1][3];
    const float rq = rsqrtf(sq * (1.f / 1536.f) + 1e-6f) * att_scale;
    const float rk = rsqrtf(sk * (1.f / 1536.f) + 1e-6f);

#pragma unroll
    for (int c = 0; c < 3; c++) {
        int p = tid + 256 * c;
        int hd = p >> 6, pl = p & 63, dd = 2 * pl;
        float cs, sn;
        if (pl < 22)      { cs = ft[t_i * 44 + 2 * pl];        sn = ft[t_i * 44 + 2 * pl + 1]; }
        else if (pl < 43) { int pp = pl - 22; cs = fh[h_i * 42 + 2 * pp]; sn = fh[h_i * 42 + 2 * pp + 1]; }
        else              { int pp = pl - 43; cs = fw[w_i * 42 + 2 * pp]; sn = fw[w_i * 42 + 2 * pp + 1]; }
        int hidx = hd * 128 + dd;
        float q0 = qv[c].x * rq * qsc[hidx], q1 = qv[c].y * rq * qsc[hidx + 1];
        float k0 = kv[c].x * rk * ksc[hidx], k1 = kv[c].y * rk * ksc[hidx + 1];
        size_t o = ((size_t)hd * N_TOK + n) * HDIM + dd;
        unsigned qo = (unsigned)f2bf(q0 * cs - q1 * sn) | ((unsigned)f2bf(q0 * sn + q1 * cs) << 16);
        unsigned ko = (unsigned)f2bf(k0 * cs - k1 * sn) | ((unsigned)f2bf(k0 * sn + k1 * cs) << 16);
        unsigned vo = (unsigned)f2bf(vv[c].x) | ((unsigned)f2bf(vv[c].y) << 16);
        *(unsigned*)(qb + o) = qo;
        *(unsigned*)(kb + o) = ko;
        *(unsigned*)(vb + o) = vo;
    }
}

// ----------------- transpose V: [head][tok][128] -> [head][128][VT_STRIDE] bf16
// Pad columns [N_TOK, VT_STRIDE) are WRITTEN AS ZERO (recycled region NaN hazard).
__global__ __launch_bounds__(256) void k_transpose_v(const unsigned short* __restrict__ vbi,
                                                     unsigned short* __restrict__ vt) {
    __shared__ unsigned short tile[32][33];
    const int head = blockIdx.z;
    const int t0 = blockIdx.x * 32, d0 = blockIdx.y * 32;
    const int tx = threadIdx.x, ty = threadIdx.y;      // 32 x 8
#pragma unroll
    for (int i = 0; i < 4; i++) {
        int t = t0 + ty + 8 * i;
        tile[ty + 8 * i][tx] = (t < N_TOK) ? vbi[((size_t)head * N_TOK + t) * HDIM + d0 + tx] : 0;
    }
    __syncthreads();
    int t = t0 + tx;                                   // < VT_STRIDE always
#pragma unroll
    for (int i = 0; i < 4; i++)
        vt[((size_t)head * HDIM + d0 + ty + 8 * i) * VT_STRIDE + t] = tile[tx][ty + 8 * i];
}

// ------------- split-KV flash attention, phase-shifted async pipeline (R7)
// Block = (q-tile 64 rows, head, split). 4 waves x 16 rows each. KV tiles of 64.
// exp2-domain softmax (log2e folded into q).  Swapped QK^T: sa[j][r] =
// S[qrow=l16][key=j*16+quad*4+r] -> lane-local softmax, b64 P writes.
//
// Pipeline (T3/T4-lite, NO extra LDS -> stays 4 blocks/CU):
//   top:   vmcnt(4) [drain K(t), V(t) in flight] ; barrier ; QK
//   post-QK barrier ; issue K(t+1)  (hidden under softmax+PV+next-QK)
//   pre-PV: vmcnt(4) [drain V(t), K(t+1) in flight] ; barrier ; PV
//   post-PV barrier ; issue V(t+1)  (hidden under next QK+softmax)
// All barriers are raw s_barrier (no compiler vmcnt(0) drain).  Each wave
// waits its OWN vmcnt then barriers => cross-wave staging visibility.
// Q global loads are oldest in the FIFO -> drained by the first vmcnt(4).
// XCD swizzle: 1104 blocks = 8 x 138; each XCD gets 3 heads' contiguous
// q-blocks (K/V slice ~2.3MB fits 4MB XCD L2).
// LDS total = 16384 (K) + 16384 (V^T) + 8192 (P) = 40960 -> 4 blocks/CU.
__global__ __launch_bounds__(256, 4) void k_attn_part(const unsigned short* __restrict__ qb,
                                                      const unsigned short* __restrict__ kb,
                                                      const unsigned short* __restrict__ vt,
                                                      float* __restrict__ Opart,
                                                      float* __restrict__ mbuf,
                                                      float* __restrict__ lbuf) {
    __shared__ __align__(16) unsigned short Ks[64 * 128];   // [key][d]   linear+swz
    __shared__ __align__(16) unsigned short Vs[128 * 64];   // [d][key]   linear+swz
    __shared__ __align__(16) unsigned short Ps[4][16 * 64]; // per-wave P [qrow][key] swz

    // XCD-aware remap (bijective: 1104 = 8*138)
    const int b = blockIdx.x + 46 * (blockIdx.y + 12 * (int)blockIdx.z);
    const int w = (b & 7) * 138 + (b >> 3);
    const int qblk = w % 46;
    const int head = (w / 46) % 12;
    const int z    = w / 552;

    const int tid = threadIdx.x, wave = tid >> 6, lane = tid & 63;
    const int quad = lane >> 4, l16 = lane & 15, x7 = l16 & 7;
    const int q0 = qblk * 64 + wave * 16;
    const unsigned short* qh = qb + (size_t)head * N_TOK * HDIM;
    const unsigned short* kh = kb + (size_t)head * N_TOK * HDIM;
    const unsigned short* vh = vt + (size_t)head * HDIM * VT_STRIDE;
    unsigned short* ps = Ps[wave];

    const int kbeg = z ? KSPLIT : 0;
    const int kend = z ? N_TOK : KSPLIT;
    const int ntile = (kend - kbeg + 63) >> 6;

    // swizzled 16B-chunk read offsets (in shorts); chunk c = ks*4+quad, row&7 = l16&7.
    int koff[4];
#pragma unroll
    for (int ks = 0; ks < 4; ks++) {
        int c = ks * 4 + quad;
        koff[ks] = ((c & 8) | ((c & 7) ^ x7)) * 8;
    }
    // P write base: row l16, chunk (j*2 + (quad>>1)) ^ x7, half (quad&1).
    const int pwq = (quad >> 1), pwh = (quad & 1) * 4;

    // staging: thread covers LDS chunk (tid + 256*i), i=0..3 (lane-linear dest).
    const int krow = tid >> 4, ksw = tid & 15;
    const int kc = (ksw & 8) | ((ksw & 7) ^ (krow & 7));   // (krow+16i)&7 == krow&7
    const int vd = tid >> 3, vsw = tid & 7;
    const int vc = vsw ^ (vd & 7);                          // (vd+32i)&7 == vd&7
    const unsigned short* ksrc = kh + (size_t)krow * HDIM + kc * 8;
    const unsigned short* vsrc = vh + (size_t)vd * VT_STRIDE + vc * 8;

    // Q fragments (loaded FIRST: oldest vmcnt entries, drained by first vmcnt(4))
    bf16x8 aq[4];
    {
        int qrow = q0 + l16;
        if (qrow < N_TOK) {
#pragma unroll
            for (int ks = 0; ks < 4; ks++)
                aq[ks] = *(const bf16x8*)&qh[(size_t)qrow * HDIM + ks * 32 + quad * 8];
        } else {
#pragma unroll
            for (int ks = 0; ks < 4; ks++) aq[ks] = (bf16x8)(__bf16)0.0f;
        }
    }

    floatx4 oacc[8] = {};
    float m_l = -1e30f;   // running max of lane's own q-row (l16)
    float l_l = 0.f;      // per-lane PARTIAL sum (reduced over quads at end)

    // ---- prologue: issue K(0) then V(0)  (4 loads each per thread-group)
    {
        const bool part0 = (kbeg + 64 > kend);
        if (!part0) {
#pragma unroll
            for (int i = 0; i < 4; i++)
                gload_lds16(ksrc + (size_t)(kbeg + 16 * i) * HDIM, &Ks[(tid + 256 * i) * 8]);
        } else {
#pragma unroll
            for (int i = 0; i < 4; i++) {
                int gk = kbeg + krow + 16 * i;
                gk = gk < N_TOK ? gk : N_TOK - 1;
                gload_lds16(kh + (size_t)gk * HDIM + kc * 8, &Ks[(tid + 256 * i) * 8]);
            }
        }
#pragma unroll
        for (int i = 0; i < 4; i++)
            gload_lds16(vsrc + (size_t)(32 * i) * VT_STRIDE + kbeg, &Vs[(tid + 256 * i) * 8]);
    }

    for (int t = 0; t < ntile; t++) {
        const int kb0 = kbeg + t * 64;
        const bool fullt = (kb0 + 64 <= kend);   // false only on last tile of z=1
        const bool has_next = (t + 1 < ntile);

        // ---- K(t) ready: drain all but the 4 newest (V(t)); cross-wave barrier
        asm volatile("s_waitcnt vmcnt(4)" ::: "memory");
        __builtin_amdgcn_sched_barrier(0);
        __builtin_amdgcn_s_barrier();

        // ---- S^T = K Q^T : sa[j][r] = S[l16][kb0 + j*16 + quad*4 + r]
        floatx4 sa[4] = {};
        __builtin_amdgcn_s_setprio(1);
#pragma unroll
        for (int j = 0; j < 4; j++)
#pragma unroll
            for (int ks = 0; ks < 4; ks++) {
                bf16x8 bkf = *(const bf16x8*)&Ks[(j * 16 + l16) * HDIM + koff[ks]];
                sa[j] = MFMA(bkf, aq[ks], sa[j]);
            }
        __builtin_amdgcn_s_setprio(0);
        __builtin_amdgcn_s_barrier();            // all waves done reading Ks

        // ---- issue K(t+1) into Ks (lands while we do softmax+PV+next wait)
        if (has_next) {
            const int kn = kb0 + 64;
            if (kn + 64 <= kend) {
#pragma unroll
                for (int i = 0; i < 4; i++)
                    gload_lds16(ksrc + (size_t)(kn + 16 * i) * HDIM, &Ks[(tid + 256 * i) * 8]);
            } else {
#pragma unroll
                for (int i = 0; i < 4; i++) {
                    int gk = kn + krow + 16 * i;
                    gk = gk < N_TOK ? gk : N_TOK - 1;
                    gload_lds16(kh + (size_t)gk * HDIM + kc * 8, &Ks[(tid + 256 * i) * 8]);
                }
            }
        }

        // ---- per-lane tile max over its 16 S values, 2 quad shuffles
        float mt;
        if (fullt) {
            float m01 = fmaxf(fmaxf(sa[0][0], sa[0][1]), fmaxf(sa[0][2], sa[0][3]));
            float m23 = fmaxf(fmaxf(sa[1][0], sa[1][1]), fmaxf(sa[1][2], sa[1][3]));
            float m45 = fmaxf(fmaxf(sa[2][0], sa[2][1]), fmaxf(sa[2][2], sa[2][3]));
            float m67 = fmaxf(fmaxf(sa[3][0], sa[3][1]), fmaxf(sa[3][2], sa[3][3]));
            mt = fmaxf(fmaxf(m01, m23), fmaxf(m45, m67));
        } else {
            mt = -1e30f;
            const int kq = kb0 + quad * 4;
#pragma unroll
            for (int j = 0; j < 4; j++)
#pragma unroll
                for (int r = 0; r < 4; r++)
                    mt = fmaxf(mt, (kq + j * 16 + r < kend) ? sa[j][r] : -1e30f);
        }
        mt = fmaxf(mt, __shfl_xor(mt, 16));
        mt = fmaxf(mt, __shfl_xor(mt, 32));

        // ---- defer-max (T13, THR=8 in exp2 domain)
        if (__any(mt > m_l + 8.f)) {
            float mn = fmaxf(m_l, mt);
            float alpha = exp2f(m_l - mn);
            m_l = mn;
            l_l *= alpha;
#pragma unroll
            for (int r = 0; r < 4; r++) {
                float ar = __shfl(alpha, quad * 4 + r, 16);
#pragma unroll
                for (int jd = 0; jd < 8; jd++) oacc[jd][r] *= ar;
            }
        }

        // ---- P = exp2(S - m): 4 keys/lane/j, packed bf16 -> ds_write_b64
        if (fullt) {
#pragma unroll
            for (int j = 0; j < 4; j++) {
                float p0 = exp2f(sa[j][0] - m_l), p1 = exp2f(sa[j][1] - m_l);
                float p2 = exp2f(sa[j][2] - m_l), p3 = exp2f(sa[j][3] - m_l);
                l_l += (p0 + p1) + (p2 + p3);
                uint2 wv;
                wv.x = (unsigned)__builtin_bit_cast(unsigned short, (__bf16)p0) |
                       ((unsigned)__builtin_bit_cast(unsigned short, (__bf16)p1) << 16);
                wv.y = (unsigned)__builtin_bit_cast(unsigned short, (__bf16)p2) |
                       ((unsigned)__builtin_bit_cast(unsigned short, (__bf16)p3) << 16);
                *(uint2*)&ps[l16 * 64 + (((j * 2 + pwq) ^ x7) << 3) + pwh] = wv;
            }
        } else {
            const int kq = kb0 + quad * 4;
#pragma unroll
            for (int j = 0; j < 4; j++) {
                float p[4];
#pragma unroll
                for (int r = 0; r < 4; r++) {
                    p[r] = (kq + j * 16 + r < kend) ? exp2f(sa[j][r] - m_l) : 0.f;
                    l_l += p[r];
                }
                uint2 wv;
                wv.x = (unsigned)__builtin_bit_cast(unsigned short, (__bf16)p[0]) |
                       ((unsigned)__builtin_bit_cast(unsigned short, (__bf16)p[1]) << 16);
                wv.y = (unsigned)__builtin_bit_cast(unsigned short, (__bf16)p[2]) |
                       ((unsigned)__builtin_bit_cast(unsigned short, (__bf16)p[3]) << 16);
                *(uint2*)&ps[l16 * 64 + (((j * 2 + pwq) ^ x7) << 3) + pwh] = wv;
            }
        }

        // ---- V(t) ready: drain all but K(t+1) (4 if issued, else 0); barrier
        if (has_next) { asm volatile("s_waitcnt vmcnt(4)" ::: "memory"); }
        else          { asm volatile("s_waitcnt vmcnt(0)" ::: "memory"); }
        __builtin_amdgcn_sched_barrier(0);
        __builtin_amdgcn_s_barrier();

        // ---- O += P V
        __builtin_amdgcn_s_setprio(1);
#pragma unroll
        for (int ks = 0; ks < 2; ks++) {
            bf16x8 ap = *(const bf16x8*)&ps[l16 * 64 + koff[ks]];
#pragma unroll
            for (int jd = 0; jd < 8; jd++) {
                bf16x8 bvf = *(const bf16x8*)&Vs[(jd * 16 + l16) * 64 + koff[ks]];
                oacc[jd] = MFMA(ap, bvf, oacc[jd]);
            }
        }
        __builtin_amdgcn_s_setprio(0);
        __builtin_amdgcn_s_barrier();            // all waves done reading Vs

        // ---- issue V(t+1) (lands while next tile does QK+softmax)
        if (has_next) {
            const int kn = kb0 + 64;
#pragma unroll
            for (int i = 0; i < 4; i++)
                gload_lds16(vsrc + (size_t)(32 * i) * VT_STRIDE + kn, &Vs[(tid + 256 * i) * 8]);
        }
    }

    // ---- reduce l partials across quads (lanes sharing l16)
    l_l += __shfl_xor(l_l, 16);
    l_l += __shfl_xor(l_l, 32);

    // ---- store un-normalized O + (m,l)
#pragma unroll
    for (int r = 0; r < 4; r++) {
        int rg = q0 + quad * 4 + r;
        if (rg < N_TOK) {
            size_t rbase = ((size_t)(z * NHEAD + head) * N_TOK + rg) * HDIM;
#pragma unroll
            for (int jd = 0; jd < 8; jd++)
                Opart[rbase + jd * 16 + l16] = oacc[jd][r];
        }
    }
    if (quad == 0 && q0 + l16 < N_TOK) {
        int mi = (z * NHEAD + head) * N_TOK + q0 + l16;
        mbuf[mi] = m_l;
        lbuf[mi] = l_l;
    }
}

// ----------------------------------------------- combine the two KV splits
__global__ __launch_bounds__(256) void k_combine(const float* __restrict__ Opart,
                                                 const float* __restrict__ mbuf,
                                                 const float* __restrict__ lbuf,
                                                 unsigned short* __restrict__ ab) {
    const int R = NHEAD * N_TOK;
    int r = blockIdx.x * 8 + (threadIdx.x >> 5);
    if (r >= R) return;
    int l32 = threadIdx.x & 31;
    float m0 = mbuf[r], m1 = mbuf[R + r];
    float l0 = lbuf[r], l1 = lbuf[R + r];
    float m = fmaxf(m0, m1);
    float w0 = exp2f(m0 - m), w1 = exp2f(m1 - m);
    float inv = 1.f / (l0 * w0 + l1 * w1);
    w0 *= inv; w1 *= inv;
    float4 a = *(const float4*)&Opart[(size_t)r * HDIM + l32 * 4];
    float4 b = *(const float4*)&Opart[((size_t)R + r) * HDIM + l32 * 4];
    int head = r / N_TOK, tok = r % N_TOK;
    unsigned short* o = ab + (size_t)tok * DMODEL + head * HDIM + l32 * 4;
    uint2 pk;
    pk.x = (unsigned)f2bf(a.x * w0 + b.x * w1) | ((unsigned)f2bf(a.y * w0 + b.y * w1) << 16);
    pk.y = (unsigned)f2bf(a.z * w0 + b.z * w1) | ((unsigned)f2bf(a.w * w0 + b.w * w1) << 16);
    *(uint2*)o = pk;
}

// ---------------------------------------------------------------------------
extern "C" void kernel_launch(void* const* d_in, const int* in_sizes, int n_in,
                              void* d_out, int out_size, void* d_ws, size_t ws_size,
                              hipStream_t stream) {
    const float* x   = (const float*)d_in[0];
    const float* Wq  = (const float*)d_in[1];
    const float* bq  = (const float*)d_in[2];
    const float* Wk  = (const float*)d_in[3];
    const float* bk  = (const float*)d_in[4];
    const float* Wv  = (const float*)d_in[5];
    const float* bv  = (const float*)d_in[6];
    const float* Wo  = (const float*)d_in[7];
    const float* bo  = (const float*)d_in[8];
    const float* qsc = (const float*)d_in[9];
    const float* ksc = (const float*)d_in[10];
    const float* ft  = (const float*)d_in[11];
    const float* fh  = (const float*)d_in[12];
    const float* fw  = (const float*)d_in[13];

    // Layout note: ab sits BEFORE the fp32 region so the O-GEMM's A-tile
    // over-reads (rows 2925..2943) land inside d_ws, never past its end.
    char* ws = (char*)d_ws;
    unsigned short* xb   = (unsigned short*)ws; ws += (size_t)N_TOK * DMODEL * 2;          // 8,985,600
    unsigned short* Wt   = (unsigned short*)ws; ws += (size_t)4 * DMODEL * DMODEL * 2;     // 18,874,368
    unsigned short* ab   = (unsigned short*)ws; ws += (size_t)N_TOK * DMODEL * 2;          // 8,985,600
    char* qkvf_region    = ws;                  ws += (size_t)3 * N_TOK * DMODEL * 4;      // 53,913,600
    unsigned short* qkvb = (unsigned short*)ws; ws += (size_t)3 * N_TOK * DMODEL * 2;      // 26,956,800

    // Phase 1: qkvf_region holds fp32 QKV projections (53.9 MB).
    float* Qf = (float*)qkvf_region;
    float* Kf = Qf + (size_t)N_TOK * DMODEL;
    float* Vf = Qf + (size_t)2 * N_TOK * DMODEL;
    // Phase 2 (after k_norm_rope): Opart 35.9MB | m/l 0.56MB | vt 9.04MB = 45.5MB.
    float* Opart = (float*)qkvf_region;
    float* mbuf  = Opart + (size_t)2 * NHEAD * N_TOK * HDIM;
    float* lbuf  = mbuf + (size_t)2 * NHEAD * N_TOK;
    unsigned short* vtp = (unsigned short*)(lbuf + (size_t)2 * NHEAD * N_TOK);

    unsigned short* qbp = qkvb;
    unsigned short* kbp = qkvb + (size_t)N_TOK * DMODEL;
    unsigned short* vbp = qkvb + (size_t)2 * N_TOK * DMODEL;

    const int nelem = N_TOK * DMODEL;
    k_convert_x<<<(nelem / 4 + 255) / 256, 256, 0, stream>>>(x, xb, nelem);
    k_transpose_w<<<dim3(48, 48, 4), dim3(32, 8), 0, stream>>>(Wq, Wk, Wv, Wo, Wt);
    k_gemm<<<dim3(12, 23, 3), 256, 0, stream>>>(xb, Wt, bq, bk, bv, Qf, N_TOK);
    k_norm_rope<<<N_TOK, 256, 0, stream>>>(Qf, Kf, Vf, qsc, ksc, ft, fh, fw, qbp, kbp, vbp);
    k_transpose_v<<<dim3(92, 4, NHEAD), dim3(32, 8), 0, stream>>>(vbp, vtp);
    k_attn_part<<<dim3(46, NHEAD, 2), 256, 0, stream>>>(qbp, kbp, vtp, Opart, mbuf, lbuf);
    k_combine<<<(NHEAD * N_TOK + 7) / 8, 256, 0, stream>>>(Opart, mbuf, lbuf, ab);
    k_gemm<<<dim3(12, 23, 1), 256, 0, stream>>>(ab, Wt + (size_t)3 * DMODEL * DMODEL,
                                                bo, bo, bo, (float*)d_out, N_TOK);
}